// Round 18
// baseline (53.334 us; speedup 1.0000x reference)
//
#include <hip/hip_runtime.h>

// n = 8192 points, d = 512, fp32 in, scalar fp32 out.
// Pipeline:
//   (1) fp32 -> fp8 e4m3 convert (+ zero-init u32 argmax keys)
//   (2) triangular fused MX-fp8 MFMA GEMM, BARRIER-FREE 1-wave blocks:
//       each 64-thread block owns a 64x64 tile (2x2 of 32x32x64 MX MFMA),
//       stages its own A/B rotation subtiles (double-buffered 16 KB LDS),
//       counted vmcnt + intra-wave lgkm waits only — zero s_barrier.
//       u32-key dual argmax: key = (mono(v)&0xFFFFE000) | (8191-idx).
//   (3) per-row ||x - x[I] + 1e-6||_2 -> log   (full fp32)
//   (4) deterministic mean reduce.

#define NPTS 8192
#define DIM  512
#define BT   64
#define NTIL 128
#define NBLK (NTIL * (NTIL + 1) / 2)   // 8256 = 8*1032 (XCD-divisible)
#define KT_N 8                          // 512 / 64

typedef float f32x16 __attribute__((ext_vector_type(16)));
typedef int   i32x4  __attribute__((ext_vector_type(4)));
typedef int   i32x8  __attribute__((ext_vector_type(8)));

// f32 -> OCP e4m3fn, round-to-nearest-even; N(0,1) data never clamps.
__device__ __forceinline__ unsigned char f32_to_e4m3(float f) {
  unsigned u = __builtin_bit_cast(unsigned, f);
  unsigned s = (u >> 24) & 0x80u;
  unsigned a = u & 0x7FFFFFFFu;
  float af = __builtin_bit_cast(float, a);
  if (af < 0.015625f) {                    // below min normal 2^-6
    int m = (int)rintf(af * 512.0f);       // RNE
    return (unsigned char)(s | (unsigned)m);
  }
  unsigned u2 = a + 0x0007FFFFu + ((a >> 20) & 1u);  // RNE to 3-bit mantissa
  int e = (int)(u2 >> 23) - 127 + 7;
  unsigned m = (u2 >> 20) & 7u;
  if (e > 15) return (unsigned char)(s | 0x7Eu);     // clamp to 448
  return (unsigned char)(s | ((unsigned)e << 3) | m);
}

// Order-preserving f32 -> u32 (branchless).
__device__ __forceinline__ unsigned int mono_f32(float f) {
  unsigned u = __builtin_bit_cast(unsigned, f);
  return u ^ (0x80000000u | (unsigned)((int)u >> 31));
}

__global__ void cvt_fp8_kernel(const float* __restrict__ x,
                               unsigned char* __restrict__ xq,
                               unsigned* __restrict__ nn32) {
  int i = blockIdx.x * blockDim.x + threadIdx.x;     // 8 elems per thread
  const float4* xp = reinterpret_cast<const float4*>(x) + 2 * (size_t)i;
  float4 v0 = xp[0], v1 = xp[1];
  unsigned long long w =
      (unsigned long long)f32_to_e4m3(v0.x) |
      ((unsigned long long)f32_to_e4m3(v0.y) << 8) |
      ((unsigned long long)f32_to_e4m3(v0.z) << 16) |
      ((unsigned long long)f32_to_e4m3(v0.w) << 24) |
      ((unsigned long long)f32_to_e4m3(v1.x) << 32) |
      ((unsigned long long)f32_to_e4m3(v1.y) << 40) |
      ((unsigned long long)f32_to_e4m3(v1.z) << 48) |
      ((unsigned long long)f32_to_e4m3(v1.w) << 56);
  reinterpret_cast<unsigned long long*>(xq)[i] = w;
  if (i < NPTS) nn32[i] = 0u;
}

__device__ __forceinline__ void gload_lds16(const unsigned char* g,
                                            unsigned char* l) {
  __builtin_amdgcn_global_load_lds(
      (__attribute__((address_space(1))) const void*)g,
      (__attribute__((address_space(3))) void*)l, 16, 0, 0);
}

__device__ __forceinline__ unsigned umax(unsigned a, unsigned b) {
  return a > b ? a : b;
}

// Triangular fused MX-fp8 GEMM + dual argmax. 1 wave per block, NO barriers.
// grid = NBLK, block = 64. LDS: 2 buffers x (A 4KB + B 4KB) = 16 KB.
__global__ __launch_bounds__(64, 3) void tri_gemm_kernel(
    const unsigned char* __restrict__ xq,
    unsigned* __restrict__ nn32) {
  __shared__ unsigned char lds[2][8192];

  // XCD-bijective swizzle (8256 = 8*1032), then b -> (ti >= tj).
  const int orig = (int)blockIdx.x;
  int b = (orig & 7) * (NBLK >> 3) + (orig >> 3);
  int ti = (int)((sqrtf(8.0f * (float)b + 1.0f) - 1.0f) * 0.5f);
  while ((ti + 1) * (ti + 2) / 2 <= b) ++ti;
  while (ti * (ti + 1) / 2 > b) --ti;
  const int tj = b - ti * (ti + 1) / 2;

  const int lane = (int)threadIdx.x;   // 0..63
  const int l31  = lane & 31;
  const int h    = lane >> 5;          // 0..1 (k-half within MFMA)
  const int arow0 = ti * BT;
  const int bcol0 = tj * BT;

  // Staging: per operand 256 chunks of 16 B (64 rows x 64 B); lane stages
  // chunks lane, lane+64, lane+128, lane+192. Rotation layout (proven):
  // LDS slot s of row r holds global chunk (s - f(r)) & 3,
  // f(r) = ((r>>1)+(r>>3)) & 3. 8 gload_lds per lane per K-tile.
  const unsigned char* pa[4];
  const unsigned char* pb[4];
  int ldst[4];
#pragma unroll
  for (int q = 0; q < 4; ++q) {
    const int row = q * 16 + (lane >> 2);
    const int f   = ((row >> 1) + (row >> 3)) & 3;
    const int g   = ((lane & 3) - f) & 3;
    pa[q] = xq + (size_t)(arow0 + row) * DIM + (g << 4);
    pb[q] = xq + (size_t)(bcol0 + row) * DIM + (g << 4);
    ldst[q] = ((q << 6) + lane) << 4;
  }

#define STAGE(bufi, kt) do {                                                 \
    _Pragma("unroll")                                                        \
    for (int q_ = 0; q_ < 4; ++q_) {                                         \
      gload_lds16(pa[q_] + (kt) * 64, &lds[bufi][ldst[q_]]);                 \
      gload_lds16(pb[q_] + (kt) * 64, &lds[bufi][4096 + ldst[q_]]);          \
    }                                                                        \
  } while (0)

  // Fragment reads (proven R15 geometry, wr=wc=0): lane l reads row (l&31)
  // of sub-tile mi/ni (at +mi*2048), global k-chunks 2h, 2h+1; stored slots
  // (g + fr) & 3, fr = ((l31>>1)+(l31>>3)) & 3.
  const int fr = ((l31 >> 1) + (l31 >> 3)) & 3;
  const int s0 = (2 * h + fr) & 3;
  const int s1 = (2 * h + 1 + fr) & 3;
  const int aoff0 = l31 * 64 + (s0 << 4), aoff1 = l31 * 64 + (s1 << 4);
  const int boff0 = 4096 + l31 * 64 + (s0 << 4);
  const int boff1 = 4096 + l31 * 64 + (s1 << 4);

  f32x16 acc[2][2];
#pragma unroll
  for (int mi = 0; mi < 2; ++mi)
#pragma unroll
    for (int ni = 0; ni < 2; ++ni)
#pragma unroll
      for (int r = 0; r < 16; ++r) acc[mi][ni][r] = 0.f;

  // Depth-2 prologue: tiles 0,1 in flight (16 loads).
  STAGE(0, 0);
  STAGE(1, 1);

  // Barrier-free main loop: counted vmcnt for staging arrival; intra-wave
  // lgkmcnt(0) after reads makes buffer overwrite safe (data in VGPRs).
#pragma unroll
  for (int t = 0; t < KT_N; ++t) {
    const int cur = t & 1;
    if (t + 1 < KT_N) {
      asm volatile("s_waitcnt vmcnt(8)" ::: "memory");  // tile t landed
    } else {
      asm volatile("s_waitcnt vmcnt(0)" ::: "memory");
    }

    i32x4 al[2], ah[2], bl[2], bh[2];
#pragma unroll
    for (int mi = 0; mi < 2; ++mi) {
      al[mi] = *reinterpret_cast<const i32x4*>(&lds[cur][aoff0 + mi * 2048]);
      ah[mi] = *reinterpret_cast<const i32x4*>(&lds[cur][aoff1 + mi * 2048]);
    }
#pragma unroll
    for (int ni = 0; ni < 2; ++ni) {
      bl[ni] = *reinterpret_cast<const i32x4*>(&lds[cur][boff0 + ni * 2048]);
      bh[ni] = *reinterpret_cast<const i32x4*>(&lds[cur][boff1 + ni * 2048]);
    }
    asm volatile("s_waitcnt lgkmcnt(0)" ::: "memory");  // reads retired
    if (t + 2 < KT_N) STAGE(cur, t + 2);                // overwrite safe

    i32x8 a8[2], b8[2];
#pragma unroll
    for (int mi = 0; mi < 2; ++mi)
      a8[mi] = (i32x8){al[mi][0], al[mi][1], al[mi][2], al[mi][3],
                       ah[mi][0], ah[mi][1], ah[mi][2], ah[mi][3]};
#pragma unroll
    for (int ni = 0; ni < 2; ++ni)
      b8[ni] = (i32x8){bl[ni][0], bl[ni][1], bl[ni][2], bl[ni][3],
                       bh[ni][0], bh[ni][1], bh[ni][2], bh[ni][3]};
    __builtin_amdgcn_s_setprio(1);
#pragma unroll
    for (int mi = 0; mi < 2; ++mi)
#pragma unroll
      for (int ni = 0; ni < 2; ++ni)
        acc[mi][ni] = __builtin_amdgcn_mfma_scale_f32_32x32x64_f8f6f4(
            a8[mi], b8[ni], acc[mi][ni], 0, 0,   // cbsz=fp8, blgp=fp8
            0, 0x7F7F7F7F, 0, 0x7F7F7F7F);       // unit E8M0 scales
    __builtin_amdgcn_s_setprio(0);
  }
#undef STAGE

  // ---- Epilogue: dual argmax, u32 quantized keys (verbatim R15, wr=wc=0).
  // 32x32 C/D layout: col = lane&31, row_local = (reg&3)+8*(reg>>2)+4*h.
  // key = (mono(v) & 0xFFFFE000) | (8191 - idx); max => first-occurrence.
  const bool diagw = (ti == tj);

  unsigned M[2][2][16];
#pragma unroll
  for (int mi = 0; mi < 2; ++mi)
#pragma unroll
    for (int ni = 0; ni < 2; ++ni)
#pragma unroll
      for (int r = 0; r < 16; ++r)
        M[mi][ni][r] = mono_f32(acc[mi][ni][r]) & 0xFFFFE000u;

  // Row side: 32 slots (mi*16 + r), pre-merged over ni.
  unsigned K[32];
  const unsigned jb = 8191u - (unsigned)(bcol0 + l31);
#pragma unroll
  for (int mi = 0; mi < 2; ++mi)
#pragma unroll
    for (int r = 0; r < 16; ++r) {
      const int rl = (r & 3) + 8 * (r >> 2) + 4 * h;
      unsigned best = 0u;
#pragma unroll
      for (int ni = 0; ni < 2; ++ni) {
        unsigned kk = M[mi][ni][r] | (jb - (unsigned)(ni * 32));
        if (diagw && mi == ni && rl == l31) kk = 0u;
        best = umax(best, kk);
      }
      K[mi * 16 + r] = best;
    }
  // Slot-halving butterfly over lane bits 0..4: 31 shuffle-steps (u32).
#pragma unroll
  for (int k = 0; k < 5; ++k) {
    const int m = 1 << k;
    const unsigned kb = (unsigned)(lane >> k) & 1u;
#pragma unroll
    for (int i = 0; i < (16 >> k); ++i) {
      unsigned lo = K[2 * i], hi = K[2 * i + 1];
      unsigned keep = kb ? hi : lo;
      unsigned send = kb ? lo : hi;
      unsigned recv = (unsigned)__shfl_xor((int)send, m);
      K[i] = umax(keep, recv);
    }
  }
  {
    // slot s = l31: mi = s>>4, r = s&15; row uses this lane's h.
    const int s = l31;
    const int gi = arow0 + (s >> 4) * 32 +
                   ((s & 3) + 8 * ((s & 15) >> 2) + 4 * h);
    atomicMax(&nn32[gi], K[0]);      // 64 lanes -> 64 distinct rows
  }

  // Col side: in-lane merge over (mi, r) per ni, then one xor-32 exchange.
  {
    unsigned C0 = 0u, C1 = 0u;
    const unsigned ib = 8191u - (unsigned)arow0;
#pragma unroll
    for (int mi = 0; mi < 2; ++mi)
#pragma unroll
      for (int r = 0; r < 16; ++r) {
        const int rl = (r & 3) + 8 * (r >> 2) + 4 * h;
        const unsigned idxk = ib - (unsigned)(mi * 32 + rl);
        unsigned k0 = M[mi][0][r] | idxk;
        if (diagw && mi == 0 && rl == l31) k0 = 0u;
        C0 = umax(C0, k0);
        unsigned k1 = M[mi][1][r] | idxk;
        if (diagw && mi == 1 && rl == l31) k1 = 0u;
        C1 = umax(C1, k1);
      }
    unsigned keep = h ? C1 : C0;
    unsigned send = h ? C0 : C1;
    unsigned recv = (unsigned)__shfl_xor((int)send, 32);
    unsigned R = umax(keep, recv);
    const int gj = bcol0 + h * 32 + l31;   // 64 distinct cols
    atomicMax(&nn32[gj], R);
  }
}

// rho_r = ||x_r - x_{nn(r)} + 1e-6||_2 ; logs[r] = log(rho + 1e-8).
__global__ void dist_log_kernel(const float* __restrict__ x,
                                const unsigned* __restrict__ nn32,
                                float* __restrict__ logs) {
  const int row  = blockIdx.x * 4 + ((int)threadIdx.x >> 6);
  const int lane = (int)threadIdx.x & 63;
  const int nn   = 8191 - (int)(nn32[row] & 8191u);
  const float4* xr = reinterpret_cast<const float4*>(x + (size_t)row * DIM);
  const float4* xn = reinterpret_cast<const float4*>(x + (size_t)nn  * DIM);
  float s = 0.f;
#pragma unroll
  for (int i = 0; i < 2; ++i) {
    float4 a = xr[lane + i * 64];
    float4 b = xn[lane + i * 64];
    float d0 = a.x - b.x + 1e-6f;
    float d1 = a.y - b.y + 1e-6f;
    float d2 = a.z - b.z + 1e-6f;
    float d3 = a.w - b.w + 1e-6f;
    s += d0 * d0 + d1 * d1 + d2 * d2 + d3 * d3;
  }
#pragma unroll
  for (int m = 32; m >= 1; m >>= 1) s += __shfl_xor(s, m);
  if (lane == 0) logs[row] = logf(sqrtf(s) + 1e-8f);
}

// Deterministic mean: 1024 threads x 8 sequential adds + LDS tree.
__global__ void final_reduce_kernel(const float* __restrict__ logs,
                                    float* __restrict__ out) {
  __shared__ float sm[1024];
  const int t = (int)threadIdx.x;
  float s = 0.f;
#pragma unroll
  for (int i = 0; i < 8; ++i) s += logs[t * 8 + i];
  sm[t] = s;
  __syncthreads();
  for (int k = 512; k > 0; k >>= 1) {
    if (t < k) sm[t] += sm[t + k];
    __syncthreads();
  }
  if (t == 0) out[0] = -(sm[0] / (float)NPTS);
}

extern "C" void kernel_launch(void* const* d_in, const int* in_sizes, int n_in,
                              void* d_out, int out_size, void* d_ws, size_t ws_size,
                              hipStream_t stream) {
  const float* x = (const float*)d_in[0];
  float* out = (float*)d_out;
  char* ws = (char*)d_ws;

  // Workspace layout (bytes):
  unsigned char* xq   = (unsigned char*)(ws);            // 4 MB
  unsigned*      nn32 = (unsigned*)(ws + 4194304);       // 32 KB
  float*         logs = (float*)(ws + 4227072);          // 32 KB

  cvt_fp8_kernel<<<(NPTS * DIM / 8) / 256, 256, 0, stream>>>(x, xq, nn32);

  tri_gemm_kernel<<<NBLK, 64, 0, stream>>>(xq, nn32);

  dist_log_kernel<<<NPTS / 4, 256, 0, stream>>>(x, nn32, logs);

  final_reduce_kernel<<<1, 1024, 0, stream>>>(logs, out);
}